// Round 7
// baseline (2356.106 us; speedup 1.0000x reference)
//
#include <hip/hip_runtime.h>
#include <cstddef>

static constexpr int Nn   = 50000;
static constexpr int Ee   = 800000;
static constexpr int LGEe = 1600000;

typedef __attribute__((ext_vector_type(8))) short bf16x8;
typedef __attribute__((ext_vector_type(4))) float f32x4;

__device__ __forceinline__ float bf2f(unsigned int u16) {
  return __uint_as_float(u16 << 16);
}
__device__ __forceinline__ unsigned int f2bf(float f) {   // RNE (output writes)
  unsigned int u = __float_as_uint(f);
  u += 0x7fffu + ((u >> 16) & 1u);
  return u >> 16;
}

// ---------------- CSR build kernels ----------------
__global__ __launch_bounds__(256)
void k_count_direct(const int* __restrict__ idx, int* __restrict__ cnt, int n) {
  int i = blockIdx.x * 256 + threadIdx.x;
  if (i < n) atomicAdd(&cnt[idx[i]], 1);
}
__global__ __launch_bounds__(256)
void k_scan1(const int* __restrict__ in, int* __restrict__ out,
             int* __restrict__ bsum, int n) {
  __shared__ int sd[256];
  int tid = threadIdx.x;
  int base = blockIdx.x * 1024 + tid * 4;
  int4 v = {0, 0, 0, 0};
  if (base < n) v = *(const int4*)(in + base);   // n % 4 == 0 for all uses
  int s = v.x + v.y + v.z + v.w;
  sd[tid] = s; __syncthreads();
  for (int off = 1; off < 256; off <<= 1) {
    int t_ = (tid >= off) ? sd[tid - off] : 0; __syncthreads();
    sd[tid] += t_; __syncthreads();
  }
  int excl = sd[tid] - s;
  if (base < n) {
    int4 o; o.x = excl; o.y = o.x + v.x; o.z = o.y + v.y; o.w = o.z + v.z;
    *(int4*)(out + base) = o;
  }
  if (tid == 255) bsum[blockIdx.x] = sd[255];
}
__global__ __launch_bounds__(1024)
void k_scan2(int* __restrict__ b, int nb) {
  __shared__ int sd[1024];
  int tid = threadIdx.x;
  int v = (tid < nb) ? b[tid] : 0;
  sd[tid] = v; __syncthreads();
  for (int off = 1; off < 1024; off <<= 1) {
    int t_ = (tid >= off) ? sd[tid - off] : 0; __syncthreads();
    sd[tid] += t_; __syncthreads();
  }
  if (tid < nb) b[tid] = sd[tid] - v;
}
// also copies final pointers into cur (fills then atomicAdd cur directly)
__global__ __launch_bounds__(256)
void k_scan3(int* __restrict__ out, const int* __restrict__ bsum, int n, int total,
             int* __restrict__ cur) {
  int i = blockIdx.x * 256 + threadIdx.x;
  if (i < n) {
    int v = out[i] + bsum[i >> 10];
    out[i] = v;
    cur[i] = v;
  }
  if (i == 0) out[n] = total;
}
__global__ __launch_bounds__(256)
void k_fillA(const int* __restrict__ dlg, const int* __restrict__ slg,
             int* __restrict__ cur, int* __restrict__ ent, int n) {
  int m = blockIdx.x * 256 + threadIdx.x;
  if (m >= n) return;
  int pos = atomicAdd(&cur[dlg[m]], 1);
  ent[pos] = slg[m];
}
// merged H0|H1 incidence fill: i in [0,2E), value = edge id (i mod E)
__global__ __launch_bounds__(256)
void k_fillC2(const int* __restrict__ H, int* __restrict__ cur,
              int* __restrict__ ent, int n2, int E) {
  int i = blockIdx.x * 256 + threadIdx.x;
  if (i >= n2) return;
  int pos = atomicAdd(&cur[H[i]], 1);
  ent[pos] = (i >= E) ? i - E : i;
}
__global__ __launch_bounds__(256)
void k_fillD(const int* __restrict__ dstA, const int* __restrict__ srcA,
             int* __restrict__ cur, int* __restrict__ ent, int n) {
  int e = blockIdx.x * 256 + threadIdx.x;
  if (e >= n) return;
  int pos = atomicAdd(&cur[dstA[e]], 1);
  ent[pos] = srcA[e];
}
__global__ __launch_bounds__(256)
void k_rdeg(const int* __restrict__ ptr, float* __restrict__ r, int n) {
  int i = blockIdx.x * 256 + threadIdx.x;
  if (i < n) r[i] = 1.0f / fmaxf((float)(ptr[i + 1] - ptr[i]), 1.0f);
}

// ---------------- dense MFMA GEMM (split-bf16, truncation split), 64-row tile ----
// C1 = act( rowmul(reluA(A)) @ W1 ) (+beta1*C1); if DUAL: C2 = act( ... @ W2 ).
// In-place C1==A is safe (each block stages its own rows before writing them).
#define MG_SWEEP(WP, ACC)                                                       \
  {                                                                             \
    bf16x8 Bh[2][4], Bl[2][4];                                                  \
    _Pragma("unroll")                                                           \
    for (int np = 0; np < 2; ++np) {                                            \
      int n = (wv * 2 + np) * 16 + nrow;                                        \
      _Pragma("unroll")                                                         \
      for (int kc = 0; kc < 4; ++kc) {                                          \
        int kr0 = kh * 128 + kc * 32 + kg * 8;                                  \
        _Pragma("unroll")                                                       \
        for (int j = 0; j < 8; ++j) {                                           \
          float w = (WP)[(size_t)(kr0 + j) * 128 + n];                          \
          unsigned int hi = __float_as_uint(w) >> 16;                           \
          float lo = w - bf2f(hi);                                              \
          Bh[np][kc][j] = (short)(unsigned short)hi;                            \
          Bl[np][kc][j] = (short)(unsigned short)(__float_as_uint(lo) >> 16);   \
        }                                                                       \
      }                                                                         \
    }                                                                           \
    _Pragma("unroll")                                                           \
    for (int kc = 0; kc < 4; ++kc) {                                            \
      _Pragma("unroll")                                                         \
      for (int m = 0; m < 4; ++m) {                                             \
        int ss = m * 16 + nrow;                                                 \
        int idx = ss * 128 + ((kc * 32 + kg * 8) ^ ((ss & 7) << 3));            \
        bf16x8 ah = *(const bf16x8*)(sAh + idx);                                \
        bf16x8 al = *(const bf16x8*)(sAl + idx);                                \
        _Pragma("unroll")                                                       \
        for (int np = 0; np < 2; ++np) {                                        \
          ACC[m][np] = __builtin_amdgcn_mfma_f32_16x16x32_bf16(ah, Bh[np][kc], ACC[m][np], 0, 0, 0); \
          ACC[m][np] = __builtin_amdgcn_mfma_f32_16x16x32_bf16(al, Bh[np][kc], ACC[m][np], 0, 0, 0); \
          ACC[m][np] = __builtin_amdgcn_mfma_f32_16x16x32_bf16(ah, Bl[np][kc], ACC[m][np], 0, 0, 0); \
        }                                                                       \
      }                                                                         \
    }                                                                           \
  }

template <int DUAL>
__global__ __launch_bounds__(256)
void k_mgemm(int M, const float* __restrict__ A, int K,
             const float* __restrict__ W1, const float* __restrict__ W2,
             const float* __restrict__ dgA, int reluA, int act,
             float* __restrict__ C1, float* __restrict__ C2, int beta1)
{
  __shared__ __align__(16) unsigned char smem[34816];
  unsigned short* sAh = (unsigned short*)smem;            // [64][128] bf16 hi
  unsigned short* sAl = (unsigned short*)(smem + 16384);  // [64][128] bf16 lo
  float* stage = (float*)smem;                            // [64][132] f32 epilogue

  const int t = threadIdx.x, wv = t >> 6;
  const int tr = t >> 4, tc = t & 15;
  const int nrow = (t & 63) & 15, kg = (t & 63) >> 4;
  const int row0 = blockIdx.x * 64;

  f32x4 acc1[4][2], acc2[4][2];
  #pragma unroll
  for (int m = 0; m < 4; ++m)
    #pragma unroll
    for (int np = 0; np < 2; ++np) {
      acc1[m][np] = (f32x4){0.f, 0.f, 0.f, 0.f};
      if (DUAL) acc2[m][np] = (f32x4){0.f, 0.f, 0.f, 0.f};
    }

  const int nkh = K >> 7;
  #pragma unroll 1
  for (int kh = 0; kh < nkh; ++kh) {
    if (kh) __syncthreads();           // sA reads of previous half done
    #pragma unroll
    for (int j = 0; j < 8; ++j) {
      int idx = t + j * 256;           // float4 id, 0..2047
      int r = idx >> 5, c4 = idx & 31;
      int gr = row0 + r; if (gr > M - 1) gr = M - 1;
      float4 va = *(const float4*)(A + (size_t)gr * K + kh * 128 + c4 * 4);
      if (reluA) {
        va.x = fmaxf(va.x, 0.f); va.y = fmaxf(va.y, 0.f);
        va.z = fmaxf(va.z, 0.f); va.w = fmaxf(va.w, 0.f);
      }
      if (dgA) {
        float sc = dgA[gr];
        va.x *= sc; va.y *= sc; va.z *= sc; va.w *= sc;
      }
      float v[4] = {va.x, va.y, va.z, va.w};
      unsigned int h[4], l[4];
      #pragma unroll
      for (int q = 0; q < 4; ++q) {
        h[q] = __float_as_uint(v[q]) >> 16;                  // truncation split
        l[q] = __float_as_uint(v[q] - bf2f(h[q])) >> 16;
      }
      int bidx = r * 128 + ((c4 * 4) ^ ((r & 7) << 3));
      uint2 ph = {h[0] | (h[1] << 16), h[2] | (h[3] << 16)};
      uint2 pl = {l[0] | (l[1] << 16), l[2] | (l[3] << 16)};
      *(uint2*)(sAh + bidx) = ph;
      *(uint2*)(sAl + bidx) = pl;
    }
    __syncthreads();

    MG_SWEEP(W1, acc1);
    if (DUAL) MG_SWEEP(W2, acc2);
  }

  __syncthreads();
  #pragma unroll
  for (int m = 0; m < 4; ++m)
    #pragma unroll
    for (int np = 0; np < 2; ++np)
      #pragma unroll
      for (int r = 0; r < 4; ++r)
        stage[(m * 16 + kg * 4 + r) * 132 + (wv * 2 + np) * 16 + nrow] = acc1[m][np][r];
  __syncthreads();
  #pragma unroll
  for (int i = 0; i < 4; ++i) {
    int s = tr * 4 + i, gr = row0 + s;
    if (gr >= M) continue;
    const float* sp = stage + s * 132 + tc * 8;
    float4 v0 = *(const float4*)sp, v1 = *(const float4*)(sp + 4);
    float o[8] = {v0.x, v0.y, v0.z, v0.w, v1.x, v1.y, v1.z, v1.w};
    #pragma unroll
    for (int j2 = 0; j2 < 8; ++j2) {
      float vv = o[j2];
      if (act == 1)      vv = fmaxf(vv, 0.f);
      else if (act == 2) vv = vv > 0.f ? vv : 0.2f * vv;
      o[j2] = vv;
    }
    float* p = C1 + (size_t)gr * 128 + tc * 8;
    if (beta1) {
      float4 c0 = *(const float4*)p, c1 = *(const float4*)(p + 4);
      o[0] += c0.x; o[1] += c0.y; o[2] += c0.z; o[3] += c0.w;
      o[4] += c1.x; o[5] += c1.y; o[6] += c1.z; o[7] += c1.w;
    }
    *(float4*)p       = *(const float4*)&o[0];
    *(float4*)(p + 4) = *(const float4*)&o[4];
  }
  if (DUAL) {
    __syncthreads();
    #pragma unroll
    for (int m = 0; m < 4; ++m)
      #pragma unroll
      for (int np = 0; np < 2; ++np)
        #pragma unroll
        for (int r = 0; r < 4; ++r)
          stage[(m * 16 + kg * 4 + r) * 132 + (wv * 2 + np) * 16 + nrow] = acc2[m][np][r];
    __syncthreads();
    #pragma unroll
    for (int i = 0; i < 4; ++i) {
      int s = tr * 4 + i, gr = row0 + s;
      if (gr >= M) continue;
      const float* sp = stage + s * 132 + tc * 8;
      float4 v0 = *(const float4*)sp, v1 = *(const float4*)(sp + 4);
      float o[8] = {v0.x, v0.y, v0.z, v0.w, v1.x, v1.y, v1.z, v1.w};
      #pragma unroll
      for (int j2 = 0; j2 < 8; ++j2) {
        float vv = o[j2];
        if (act == 1)      vv = fmaxf(vv, 0.f);
        else if (act == 2) vv = vv > 0.f ? vv : 0.2f * vv;
        o[j2] = vv;
      }
      float* p = C2 + (size_t)gr * 128 + tc * 8;
      *(float4*)p       = *(const float4*)&o[0];
      *(float4*)(p + 4) = *(const float4*)&o[4];
    }
  }
}

// ---------------- fused TSA1 (split-bf16 MFMA): ----------------
// BUF[e] = bf16( et[e]@Ws + mean_{s in A(e)} et[s] @ Wn ), 64 segs/block.
__global__ __launch_bounds__(256)
void k_tsa1(const float* __restrict__ et,
            const int* __restrict__ rp, const int* __restrict__ ent,
            const float* __restrict__ Ws, const float* __restrict__ Wn,
            unsigned short* __restrict__ BUF)
{
  __shared__ __align__(16) unsigned char smem[34816];
  unsigned short* sAh = (unsigned short*)smem;            // [64][128] bf16 hi
  unsigned short* sAl = (unsigned short*)(smem + 16384);  // [64][128] bf16 lo
  int*   sEnt  = (int*)(smem + 32768);                    // 512 ints
  float* stage = (float*)smem;                            // [64][132] f32 (epilogue)

  const int t = threadIdx.x, wv = t >> 6, lane = t & 63;
  const int tr = t >> 4, tc = t & 15;
  const int nrow = lane & 15, kg = lane >> 4;
  const int seg0 = blockIdx.x * 64;
  const int segbase = seg0 + wv * 16;

  int rpv = (lane <= 16) ? rp[segbase + lane] : 0;
  int nxtv = __shfl(rpv, (lane + 1) & 63);
  float invv = 1.f / fmaxf((float)(nxtv - rpv), 1.f);   // valid lanes 0..15

  const int base = rp[seg0];
  const int cnt  = rp[seg0 + 64] - base;
  const int lim  = cnt < 512 ? cnt : 512;
  for (int i = t; i < lim; i += 256) sEnt[i] = ent[base + i];

  // direct half (k = lane): coalesced loads, truncation split, swizzled writes
  {
    float dv[16];
    #pragma unroll
    for (int i = 0; i < 16; ++i)
      dv[i] = et[(size_t)(segbase + i) * 64 + lane];
    #pragma unroll
    for (int i = 0; i < 16; ++i) {
      int ss = wv * 16 + i;
      unsigned int hi = __float_as_uint(dv[i]) >> 16;
      float lo = dv[i] - bf2f(hi);
      int idx = ss * 128 + (lane ^ ((ss & 7) << 3));
      sAh[idx] = (unsigned short)hi;
      sAl[idx] = (unsigned short)(__float_as_uint(lo) >> 16);
    }
  }

  // B fragments from global (L2-resident), truncation split
  bf16x8 Bh[2][4], Bl[2][4];
  #pragma unroll
  for (int np = 0; np < 2; ++np) {
    int n = (wv * 2 + np) * 16 + nrow;
    #pragma unroll
    for (int kc = 0; kc < 4; ++kc) {
      const float* Wp = (kc < 2) ? Ws : Wn;
      int kr0 = (kc & 1) * 32 + kg * 8;
      #pragma unroll
      for (int j = 0; j < 8; ++j) {
        float w = Wp[(size_t)(kr0 + j) * 128 + n];
        unsigned int hi = __float_as_uint(w) >> 16;
        float lo = w - bf2f(hi);
        Bh[np][kc][j] = (short)(unsigned short)hi;
        Bl[np][kc][j] = (short)(unsigned short)(__float_as_uint(lo) >> 16);
      }
    }
  }
  __syncthreads();   // sEnt ready

  // gathered half (k = 64+lane): flatten over entries, 8 row-loads in flight
  {
    int q0 = __shfl(rpv, 0);
    int q1 = __shfl(rpv, 16);
    int c = 0;
    int b_next = __shfl(rpv, 1);
    float idg = __shfl(invv, 0);
    float a = 0.f;
    #pragma unroll 1
    for (int j = q0; j < q1; j += 8) {
      float x[8];
      #pragma unroll
      for (int u = 0; u < 8; ++u) {
        int jj = j + u; jj = jj < q1 ? jj : q1 - 1;
        int ix = jj - base;
        int s = (ix < 512) ? sEnt[ix] : ent[jj];
        x[u] = et[(size_t)s * 64 + lane];
      }
      #pragma unroll
      for (int u = 0; u < 8; ++u) {
        int jj = j + u;
        if (jj >= q1) break;
        while (jj >= b_next) {        // column c complete -> flush
          float v = a * idg;
          int ss = wv * 16 + c;
          unsigned int hi = __float_as_uint(v) >> 16;
          float lo = v - bf2f(hi);
          int idx = ss * 128 + ((64 + lane) ^ ((ss & 7) << 3));
          sAh[idx] = (unsigned short)hi;
          sAl[idx] = (unsigned short)(__float_as_uint(lo) >> 16);
          a = 0.f;
          ++c;
          b_next = __shfl(rpv, c + 1);
          idg = __shfl(invv, c);
        }
        a += x[u];
      }
    }
    #pragma unroll 1
    for (;;) {                        // flush current + trailing columns
      float v = a * idg;
      int ss = wv * 16 + c;
      unsigned int hi = __float_as_uint(v) >> 16;
      float lo = v - bf2f(hi);
      int idx = ss * 128 + ((64 + lane) ^ ((ss & 7) << 3));
      sAh[idx] = (unsigned short)hi;
      sAl[idx] = (unsigned short)(__float_as_uint(lo) >> 16);
      a = 0.f;
      if (++c >= 16) break;
      idg = __shfl(invv, c);
    }
  }
  __syncthreads();

  f32x4 acc[4][2];
  #pragma unroll
  for (int m = 0; m < 4; ++m)
    #pragma unroll
    for (int np = 0; np < 2; ++np)
      acc[m][np] = (f32x4){0.f, 0.f, 0.f, 0.f};

  #pragma unroll
  for (int kc = 0; kc < 4; ++kc) {
    #pragma unroll
    for (int m = 0; m < 4; ++m) {
      int ss = m * 16 + nrow;
      int kbase = kc * 32 + kg * 8;
      int idx = ss * 128 + (kbase ^ ((ss & 7) << 3));
      bf16x8 ah = *(const bf16x8*)(sAh + idx);
      bf16x8 al = *(const bf16x8*)(sAl + idx);
      #pragma unroll
      for (int np = 0; np < 2; ++np) {
        acc[m][np] = __builtin_amdgcn_mfma_f32_16x16x32_bf16(ah, Bh[np][kc], acc[m][np], 0, 0, 0);
        acc[m][np] = __builtin_amdgcn_mfma_f32_16x16x32_bf16(al, Bh[np][kc], acc[m][np], 0, 0, 0);
        acc[m][np] = __builtin_amdgcn_mfma_f32_16x16x32_bf16(ah, Bl[np][kc], acc[m][np], 0, 0, 0);
      }
    }
  }

  __syncthreads();
  #pragma unroll
  for (int m = 0; m < 4; ++m)
    #pragma unroll
    for (int np = 0; np < 2; ++np)
      #pragma unroll
      for (int r = 0; r < 4; ++r)
        stage[(m * 16 + kg * 4 + r) * 132 + (wv * 2 + np) * 16 + nrow] = acc[m][np][r];
  __syncthreads();
  #pragma unroll
  for (int i = 0; i < 4; ++i) {
    int s = tr * 4 + i;
    const float* sp = stage + s * 132 + tc * 8;
    float4 v0 = *(const float4*)sp;
    float4 v1 = *(const float4*)(sp + 4);
    unsigned int pk[4];
    pk[0] = f2bf(v0.x) | (f2bf(v0.y) << 16);
    pk[1] = f2bf(v0.z) | (f2bf(v0.w) << 16);
    pk[2] = f2bf(v1.x) | (f2bf(v1.y) << 16);
    pk[3] = f2bf(v1.z) | (f2bf(v1.w) << 16);
    uint4 st = {pk[0], pk[1], pk[2], pk[3]};
    *(uint4*)(BUF + (size_t)(seg0 + s) * 128 + tc * 8) = st;
  }
}

// ---------------- fused TSA2 pooling (replaces CSR B entirely) ----------------
// Balanced chunks over CSR C entries (node -> incident edge e). Per entry:
//   OS[n] += relu(BUF[e]);  ON[n] += mean_{s in A(e)} relu(BUF[s])
// Inner walk over CSR A is wave-uniform -> uniform-branch batched loads.
// OS/ON zero-initialized; boundary segments flushed via atomicAdd.
__global__ __launch_bounds__(256)
void k_pool12(const int* __restrict__ rp, const int* __restrict__ ent,
              const int* __restrict__ rpA, const int* __restrict__ entA,
              const unsigned short* __restrict__ BUF,
              float* __restrict__ OS, float* __restrict__ ON,
              int nseg, int total)
{
  const int wv = threadIdx.x >> 6, lane = threadIdx.x & 63;
  const int chunk = blockIdx.x * 4 + wv;
  const int c0 = chunk * 128;
  if (c0 >= total) return;
  int c1 = c0 + 128; if (c1 > total) c1 = total;

  int lo = 0, hi = nseg;
  while (lo + 1 < hi) {
    int mid = (lo + hi) >> 1;
    if (rp[mid] <= c0) lo = mid; else hi = mid;
  }
  int seg = lo;
  int sstart = rp[seg];
  int send = rp[seg + 1];
  float s0 = 0.f, s1 = 0.f, n0 = 0.f, n1 = 0.f;

  #pragma unroll 1
  for (int j = c0; j < c1; j += 8) {
    int ids[8];
    #pragma unroll
    for (int u = 0; u < 8; ++u) {
      int jj = j + u; jj = jj < c1 ? jj : c1 - 1;
      ids[u] = ent[jj];
    }
    unsigned int uv[8];
    int pA0[8], pA1[8];
    #pragma unroll
    for (int u = 0; u < 8; ++u)
      uv[u] = *(const unsigned int*)(BUF + (size_t)ids[u] * 128 + 2 * lane);
    #pragma unroll
    for (int u = 0; u < 8; ++u) { pA0[u] = rpA[ids[u]]; pA1[u] = rpA[ids[u] + 1]; }
    #pragma unroll
    for (int u = 0; u < 8; ++u) {
      int jj = j + u;
      if (jj >= c1) break;
      while (jj >= send) {               // segment complete -> flush both
        float* pS = OS + (size_t)seg * 128;
        float* pN = ON + (size_t)seg * 128;
        if (sstart >= c0 && send <= c1) {
          pS[2 * lane]     += s0;  pS[2 * lane + 1] += s1;
          pN[2 * lane]     += n0;  pN[2 * lane + 1] += n1;
        } else {
          atomicAdd(pS + 2 * lane, s0);     atomicAdd(pS + 2 * lane + 1, s1);
          atomicAdd(pN + 2 * lane, n0);     atomicAdd(pN + 2 * lane + 1, n1);
        }
        s0 = s1 = n0 = n1 = 0.f;
        ++seg; sstart = send; send = rp[seg + 1];
      }
      s0 += fmaxf(bf2f(uv[u] & 0xffffu), 0.f);
      s1 += fmaxf(bf2f(uv[u] >> 16),     0.f);
      // inner: mean over A(e) (wave-uniform range -> uniform branches)
      int p0 = pA0[u], p1 = pA1[u];
      float a0 = 0.f, a1 = 0.f;
      #pragma unroll 1
      for (int t2 = p0; t2 < p1; t2 += 4) {
        unsigned int w[4];
        int rem = p1 - t2;
        #pragma unroll
        for (int v2 = 0; v2 < 4; ++v2)
          if (v2 < rem)
            w[v2] = *(const unsigned int*)(BUF + (size_t)entA[t2 + v2] * 128 + 2 * lane);
        #pragma unroll
        for (int v2 = 0; v2 < 4; ++v2)
          if (v2 < rem) {
            a0 += fmaxf(bf2f(w[v2] & 0xffffu), 0.f);
            a1 += fmaxf(bf2f(w[v2] >> 16),     0.f);
          }
      }
      float idg = 1.f / fmaxf((float)(p1 - p0), 1.f);
      n0 += a0 * idg; n1 += a1 * idg;
    }
  }
  {                                       // final flush
    float* pS = OS + (size_t)seg * 128;
    float* pN = ON + (size_t)seg * 128;
    if (sstart >= c0 && send <= c1) {
      pS[2 * lane]     += s0;  pS[2 * lane + 1] += s1;
      pN[2 * lane]     += n0;  pN[2 * lane + 1] += n1;
    } else {
      atomicAdd(pS + 2 * lane, s0);     atomicAdd(pS + 2 * lane + 1, s1);
      atomicAdd(pN + 2 * lane, n0);     atomicAdd(pN + 2 * lane + 1, n1);
    }
  }
}

// ---------------- balanced chunked segment-mean (f32 rows): O[seg] += mean ----
__global__ __launch_bounds__(256)
void k_poolf(const int* __restrict__ rp, const int* __restrict__ ent,
             const float* __restrict__ SRC, float* __restrict__ O,
             int nseg, int total)
{
  const int wv = threadIdx.x >> 6, lane = threadIdx.x & 63;
  const int chunk = blockIdx.x * 4 + wv;
  const int c0 = chunk * 256;
  if (c0 >= total) return;
  int c1 = c0 + 256; if (c1 > total) c1 = total;

  int lo = 0, hi = nseg;
  while (lo + 1 < hi) {
    int mid = (lo + hi) >> 1;
    if (rp[mid] <= c0) lo = mid; else hi = mid;
  }
  int seg = lo;
  int sstart = rp[seg];
  int send = rp[seg + 1];
  float a0 = 0.f, a1 = 0.f;

  #pragma unroll 1
  for (int j = c0; j < c1; j += 8) {
    int ids[8];
    #pragma unroll
    for (int u = 0; u < 8; ++u) {
      int jj = j + u; jj = jj < c1 ? jj : c1 - 1;
      ids[u] = ent[jj];
    }
    float2 v[8];
    #pragma unroll
    for (int u = 0; u < 8; ++u)
      v[u] = ((const float2*)(SRC + (size_t)ids[u] * 128))[lane];
    #pragma unroll
    for (int u = 0; u < 8; ++u) {
      int jj = j + u;
      if (jj >= c1) break;
      while (jj >= send) {               // segment complete -> flush mean
        float sc = 1.f / fmaxf((float)(send - sstart), 1.f);
        float* p = O + (size_t)seg * 128;
        if (sstart >= c0 && send <= c1) {
          p[2 * lane]     += a0 * sc;
          p[2 * lane + 1] += a1 * sc;
        } else {
          atomicAdd(p + 2 * lane, a0 * sc);
          atomicAdd(p + 2 * lane + 1, a1 * sc);
        }
        a0 = a1 = 0.f;
        ++seg; sstart = send; send = rp[seg + 1];
      }
      a0 += v[u].x; a1 += v[u].y;
    }
  }
  {
    float sc = 1.f / fmaxf((float)(send - sstart), 1.f);
    float* p = O + (size_t)seg * 128;
    if (sstart >= c0 && send <= c1) {
      p[2 * lane]     += a0 * sc;
      p[2 * lane + 1] += a1 * sc;
    } else {
      atomicAdd(p + 2 * lane, a0 * sc);
      atomicAdd(p + 2 * lane + 1, a1 * sc);
    }
  }
}

// ---------------- fused attention: online softmax + PV, one wave per node ----------------
__global__ __launch_bounds__(256)
void k_attn(const int* __restrict__ rp, const int* __restrict__ ent,
            const float* __restrict__ q, const float* __restrict__ kb,
            const float* __restrict__ vb, float* __restrict__ o, int nseg)
{
  int wv = threadIdx.x >> 6, lane = threadIdx.x & 63;
  int seg = blockIdx.x * 4 + wv;
  if (seg >= nseg) return;
  int p0 = rp[seg], p1 = rp[seg + 1];
  if (p0 >= p1) return;
  float2 q2 = ((const float2*)(q + (size_t)seg * 128))[lane];
  float m = -1e30f, l = 0.f, o0 = 0.f, o1 = 0.f;
  #pragma unroll 1
  for (int j = p0; j < p1; j += 4) {
    int s[4];
    #pragma unroll
    for (int i = 0; i < 4; ++i) {
      int jj = j + i; jj = jj < p1 ? jj : p1 - 1;
      s[i] = ent[jj];
    }
    float2 k2[4], v2[4];
    #pragma unroll
    for (int i = 0; i < 4; ++i)
      k2[i] = ((const float2*)(kb + (size_t)s[i] * 128))[lane];
    #pragma unroll
    for (int i = 0; i < 4; ++i)
      v2[i] = ((const float2*)(vb + (size_t)s[i] * 128))[lane];
    float d[4];
    #pragma unroll
    for (int i = 0; i < 4; ++i) d[i] = fmaf(q2.x, k2[i].x, q2.y * k2[i].y);
    #pragma unroll
    for (int off = 1; off < 64; off <<= 1) {
      #pragma unroll
      for (int i = 0; i < 4; ++i) d[i] += __shfl_xor(d[i], off);
    }
    float sc[4];
    #pragma unroll
    for (int i = 0; i < 4; ++i) {
      float v = d[i] * 0.088388347648318447f;      // 1/sqrt(128)
      v = v > 0.f ? v : 0.2f * v;                  // leaky 0.2
      sc[i] = (j + i < p1) ? v : -1e30f;
    }
    float mb = fmaxf(fmaxf(sc[0], sc[1]), fmaxf(sc[2], sc[3]));
    float mn = fmaxf(m, mb);
    float scale = expf(m - mn);
    float e[4];
    #pragma unroll
    for (int i = 0; i < 4; ++i)
      e[i] = (j + i < p1) ? expf(sc[i] - mn) : 0.f;
    l  = l  * scale + ((e[0] + e[1]) + (e[2] + e[3]));
    o0 = o0 * scale + ((e[0] * v2[0].x + e[1] * v2[1].x) + (e[2] * v2[2].x + e[3] * v2[3].x));
    o1 = o1 * scale + ((e[0] * v2[0].y + e[1] * v2[1].y) + (e[2] * v2[2].y + e[3] * v2[3].y));
    m = mn;
  }
  float inv = 1.f / fmaxf(l, 1e-9f);
  float2* orow = (float2*)(o + (size_t)seg * 128);
  float2 cur = orow[lane];
  cur.x += o0 * inv; cur.y += o1 * inv;
  orow[lane] = cur;
}

// ---------------- classifier + log_softmax ----------------
__global__ __launch_bounds__(256)
void k_out(const float* __restrict__ attn, const float* __restrict__ Wout,
           float* __restrict__ out, int n) {
  __shared__ float sW[128 * 64];
  for (int i = threadIdx.x; i < 128 * 64; i += 256) sW[i] = Wout[i];
  __syncthreads();
  int wave = threadIdx.x >> 6, lane = threadIdx.x & 63;
  int row = blockIdx.x * 4 + wave;
  if (row >= n) return;
  const float* a = attn + (size_t)row * 128;
  float z = 0.f;
  #pragma unroll 8
  for (int k = 0; k < 128; ++k) z = fmaf(a[k], sW[k * 64 + lane], z);
  float mx = z;
  #pragma unroll
  for (int off = 32; off; off >>= 1) mx = fmaxf(mx, __shfl_xor(mx, off));
  float ee = expf(z - mx);
  float ss = ee;
  #pragma unroll
  for (int off = 32; off; off >>= 1) ss += __shfl_xor(ss, off);
  out[(size_t)row * 64 + lane] = z - mx - logf(ss);
}

extern "C" void kernel_launch(void* const* d_in, const int* in_sizes, int n_in,
                              void* d_out, int out_size, void* d_ws, size_t ws_size,
                              hipStream_t stream) {
  (void)in_sizes; (void)n_in; (void)out_size;
  const float* x        = (const float*)d_in[0];
  const float* et       = (const float*)d_in[1];
  const int*   H0       = (const int*)d_in[2];   // H0,H1 contiguous
  const int*   src      = (const int*)d_in[3];
  const int*   dst      = src + Ee;
  const int*   src_lg   = (const int*)d_in[4];
  const int*   dst_lg   = src_lg + LGEe;
  const float* W_tsa1_s = (const float*)d_in[5];
  const float* W_tsa1_n = (const float*)d_in[6];
  const float* W_tsa2_s = (const float*)d_in[7];
  const float* W_tsa2_n = (const float*)d_in[8];
  const float* W_etn    = (const float*)d_in[9];
  const float* W_eg_lin = (const float*)d_in[10];
  const float* W_ea_s   = (const float*)d_in[11];
  const float* W_ea_n   = (const float*)d_in[12];
  const float* W_an1_s  = (const float*)d_in[13];
  const float* W_an1_n  = (const float*)d_in[14];
  const float* W_an2_s  = (const float*)d_in[15];
  const float* W_an2_n  = (const float*)d_in[16];
  const float* Wq       = (const float*)d_in[17];
  const float* Wk       = (const float*)d_in[18];
  const float* Wv       = (const float*)d_in[19];
  const float* W_out    = (const float*)d_in[20];
  float* out = (float*)d_out;

  // ---- workspace carve ----
  char* wp = (char*)d_ws;
  size_t avail = ws_size;
  auto alloc = [&](size_t bytes) -> void* {
    void* r = (void*)wp;
    size_t pad = (bytes + 255) & ~(size_t)255;
    wp += pad; avail = (avail >= pad) ? avail - pad : 0;
    return r;
  };
  const size_t NH = (size_t)Nn * 128;
  unsigned short* BUF = (unsigned short*)alloc((size_t)Ee * 128 * 2); // 204.8MB bf16 h1
  float* aggN  = (float*)alloc(NH * 4);
  float* aggS  = (float*)alloc(NH * 4);
  int* ptrA  = (int*)alloc(((size_t)Ee + 1) * 4);
  int* cntA  = (int*)alloc((size_t)Ee * 4);
  int* entA  = (int*)alloc((size_t)LGEe * 4);
  int* ptrC  = (int*)alloc(((size_t)Nn + 1) * 4);
  int* cntC  = (int*)alloc((size_t)Nn * 4);
  int* entC  = (int*)alloc((size_t)2 * Ee * 4);
  int* ptrD  = (int*)alloc(((size_t)Nn + 1) * 4);
  int* cntD  = (int*)alloc((size_t)Nn * 4);
  int* entD  = (int*)alloc((size_t)Ee * 4);
  float* rdegN = (float*)alloc((size_t)Nn * 4);
  int* bsum  = (int*)alloc(2048 * 4);
  if (avail == 0 && wp > (char*)d_ws + ws_size) return;  // ws too small: clean fail

  // node-phase f32 arrays overlay BUF (dead after k_pool12): 8 x 25.6MB
  float* er  = (float*)BUF + 0 * NH;
  float* ae  = (float*)BUF + 1 * NH;
  float* hn  = (float*)BUF + 2 * NH;
  float* hn2 = (float*)BUF + 3 * NH;
  float* qb  = (float*)BUF + 4 * NH;
  float* kb  = (float*)BUF + 5 * NH;
  float* vb  = (float*)BUF + 6 * NH;
  float* tmp = (float*)BUF + 7 * NH;

  auto cdiv = [](long a, long b) { return (int)((a + b - 1) / b); };
  auto scan = [&](int* cnt, int* ptr, int n, int total) {
    int nb = cdiv(n, 1024);
    k_scan1<<<nb, 256, 0, stream>>>(cnt, ptr, bsum, n);
    k_scan2<<<1, 1024, 0, stream>>>(bsum, nb);
    k_scan3<<<cdiv(n, 256), 256, 0, stream>>>(ptr, bsum, n, total, cnt); // cnt becomes cur
  };

  const int gLG = cdiv(LGEe, 256), gEe = cdiv(Ee, 256), g2E = cdiv(2 * Ee, 256);

  // ---- CSR A: line-graph by dst_lg (E segments) ----
  hipMemsetAsync(cntA, 0, (size_t)Ee * 4, stream);
  k_count_direct<<<gLG, 256, 0, stream>>>(dst_lg, cntA, LGEe);
  scan(cntA, ptrA, Ee, LGEe);
  k_fillA<<<gLG, 256, 0, stream>>>(dst_lg, src_lg, cntA, entA, LGEe);

  // ---- CSR C: H incidence (N segments, 2E entries), merged H0|H1 passes ----
  hipMemsetAsync(cntC, 0, (size_t)Nn * 4, stream);
  k_count_direct<<<g2E, 256, 0, stream>>>(H0, cntC, 2 * Ee);
  scan(cntC, ptrC, Nn, 2 * Ee);
  k_fillC2<<<g2E, 256, 0, stream>>>(H0, cntC, entC, 2 * Ee, Ee);

  // ---- CSR D: raw graph by dst (N segments, E entries, value = src) ----
  hipMemsetAsync(cntD, 0, (size_t)Nn * 4, stream);
  k_count_direct<<<gEe, 256, 0, stream>>>(dst, cntD, Ee);
  scan(cntD, ptrD, Nn, Ee);
  k_fillD<<<gEe, 256, 0, stream>>>(dst, src, cntD, entD, Ee);
  k_rdeg<<<cdiv(Nn, 256), 256, 0, stream>>>(ptrC, rdegN, Nn);

  const int gM64  = cdiv(Nn, 64);                       // 782
  const int gW    = cdiv(Nn, 4);                        // 12500
  const int gP12  = cdiv(cdiv(2 * Ee, 128), 4);         // 3125
  const int gPf   = cdiv(cdiv(Ee, 256), 4);             // 782

  // ---- TSA layer 1, fused self+nbr -> BUF (bf16, pre-relu), split-bf16 MFMA ----
  k_tsa1<<<Ee / 64, 256, 0, stream>>>(et, ptrA, entA, W_tsa1_s, W_tsa1_n, BUF);

  // ---- TSA layer 2 + EdgeToNode: fused nested pooling (no CSR B) ----
  hipMemsetAsync(aggS, 0, NH * 4, stream);
  hipMemsetAsync(aggN, 0, NH * 4, stream);
  k_pool12<<<gP12, 256, 0, stream>>>(ptrC, entC, ptrA, entA, BUF, aggS, aggN, Nn, 2 * Ee);
  k_mgemm<0><<<gM64, 256, 0, stream>>>(Nn, aggN, 128, W_tsa2_n, nullptr, nullptr, 0, 0, aggN, nullptr, 0); // in-place
  k_mgemm<0><<<gM64, 256, 0, stream>>>(Nn, aggS, 128, W_tsa2_s, nullptr, nullptr, 0, 0, aggN, nullptr, 1);
  k_mgemm<0><<<gM64, 256, 0, stream>>>(Nn, aggN, 128, W_etn, nullptr, rdegN, 0, 2, tmp, nullptr, 0);
  k_mgemm<0><<<gM64, 256, 0, stream>>>(Nn, tmp, 128, W_eg_lin, nullptr, nullptr, 0, 0, er, nullptr, 0);

  // ---- edge_aggr SAGE (dual: ae = er@Ws, tmp = er@Wn) ----
  k_mgemm<1><<<gM64, 256, 0, stream>>>(Nn, er, 128, W_ea_s, W_ea_n, nullptr, 0, 0, ae, tmp, 0);
  k_poolf<<<gPf, 256, 0, stream>>>(ptrD, entD, tmp, ae, Nn, Ee);

  // ---- attr_node_model (dual pairs; hn kept pre-relu, relu applied on read) ----
  k_mgemm<1><<<gM64, 256, 0, stream>>>(Nn, x, 256, W_an1_s, W_an1_n, nullptr, 0, 0, hn, tmp, 0);
  k_poolf<<<gPf, 256, 0, stream>>>(ptrD, entD, tmp, hn, Nn, Ee);
  k_mgemm<1><<<gM64, 256, 0, stream>>>(Nn, hn, 128, W_an2_s, W_an2_n, nullptr, 1, 0, hn2, tmp, 0);
  k_poolf<<<gPf, 256, 0, stream>>>(ptrD, entD, tmp, hn2, Nn, Ee);

  // ---- MixAttention (fused online softmax; out accumulated into hn2) ----
  k_mgemm<0><<<gM64, 256, 0, stream>>>(Nn, hn2, 128, Wq, nullptr, nullptr, 0, 0, qb, nullptr, 0);
  k_mgemm<1><<<gM64, 256, 0, stream>>>(Nn, ae, 128, Wk, Wv, nullptr, 0, 0, kb, vb, 0);
  k_attn<<<gW, 256, 0, stream>>>(ptrD, entD, qb, kb, vb, hn2, Nn);

  // ---- classifier + log_softmax ----
  k_out<<<gW, 256, 0, stream>>>(hn2, W_out, out, Nn);
}

// Round 8
// 2330.973 us; speedup vs baseline: 1.0108x; 1.0108x over previous
//
#include <hip/hip_runtime.h>
#include <cstddef>

static constexpr int Nn   = 50000;
static constexpr int Ee   = 800000;
static constexpr int LGEe = 1600000;

typedef __attribute__((ext_vector_type(8))) short bf16x8;
typedef __attribute__((ext_vector_type(4))) float f32x4;

__device__ __forceinline__ float bf2f(unsigned int u16) {
  return __uint_as_float(u16 << 16);
}
__device__ __forceinline__ unsigned int f2bf(float f) {   // RNE (output writes)
  unsigned int u = __float_as_uint(f);
  u += 0x7fffu + ((u >> 16) & 1u);
  return u >> 16;
}

// ---------------- CSR build kernels ----------------
__global__ __launch_bounds__(256)
void k_count_direct(const int* __restrict__ idx, int* __restrict__ cnt, int n) {
  int i = blockIdx.x * 256 + threadIdx.x;
  if (i < n) atomicAdd(&cnt[idx[i]], 1);
}
// merged H0|H1 composed count: i in [0,2*LGE)
__global__ __launch_bounds__(256)
void k_count_comp2(const int* __restrict__ H, const int* __restrict__ dlg,
                   int* __restrict__ cnt, int n2, int LGE, int E) {
  int i = blockIdx.x * 256 + threadIdx.x;
  if (i >= n2) return;
  int b = i >= LGE;
  int m = b ? i - LGE : i;
  atomicAdd(&cnt[H[b * E + dlg[m]]], 1);
}
__global__ __launch_bounds__(256)
void k_scan1(const int* __restrict__ in, int* __restrict__ out,
             int* __restrict__ bsum, int n) {
  __shared__ int sd[256];
  int tid = threadIdx.x;
  int base = blockIdx.x * 1024 + tid * 4;
  int4 v = {0, 0, 0, 0};
  if (base < n) v = *(const int4*)(in + base);   // n % 4 == 0 for all uses
  int s = v.x + v.y + v.z + v.w;
  sd[tid] = s; __syncthreads();
  for (int off = 1; off < 256; off <<= 1) {
    int t_ = (tid >= off) ? sd[tid - off] : 0; __syncthreads();
    sd[tid] += t_; __syncthreads();
  }
  int excl = sd[tid] - s;
  if (base < n) {
    int4 o; o.x = excl; o.y = o.x + v.x; o.z = o.y + v.y; o.w = o.z + v.z;
    *(int4*)(out + base) = o;
  }
  if (tid == 255) bsum[blockIdx.x] = sd[255];
}
__global__ __launch_bounds__(1024)
void k_scan2(int* __restrict__ b, int nb) {
  __shared__ int sd[1024];
  int tid = threadIdx.x;
  int v = (tid < nb) ? b[tid] : 0;
  sd[tid] = v; __syncthreads();
  for (int off = 1; off < 1024; off <<= 1) {
    int t_ = (tid >= off) ? sd[tid - off] : 0; __syncthreads();
    sd[tid] += t_; __syncthreads();
  }
  if (tid < nb) b[tid] = sd[tid] - v;
}
// also copies final pointers into cur (fills then atomicAdd cur directly)
__global__ __launch_bounds__(256)
void k_scan3(int* __restrict__ out, const int* __restrict__ bsum, int n, int total,
             int* __restrict__ cur) {
  int i = blockIdx.x * 256 + threadIdx.x;
  if (i < n) {
    int v = out[i] + bsum[i >> 10];
    out[i] = v;
    cur[i] = v;
  }
  if (i == 0) out[n] = total;
}
__global__ __launch_bounds__(256)
void k_fillA(const int* __restrict__ dlg, const int* __restrict__ slg,
             int* __restrict__ cur, int* __restrict__ ent, int n) {
  int m = blockIdx.x * 256 + threadIdx.x;
  if (m >= n) return;
  int pos = atomicAdd(&cur[dlg[m]], 1);
  ent[pos] = slg[m];
}
// merged H0|H1 composed fill: i in [0,2*LGE)
__global__ __launch_bounds__(256)
void k_fillB2(const int* __restrict__ H, const int* __restrict__ dlg,
              const int* __restrict__ slg, const int* __restrict__ ptrA,
              int* __restrict__ cur, int* __restrict__ entS,
              float* __restrict__ entW, int n2, int LGE, int E) {
  int i = blockIdx.x * 256 + threadIdx.x;
  if (i >= n2) return;
  int b = i >= LGE;
  int m = b ? i - LGE : i;
  int d = dlg[m];
  int pos = atomicAdd(&cur[H[b * E + d]], 1);
  entS[pos] = slg[m];
  int la = ptrA[d + 1] - ptrA[d];
  entW[pos] = 1.0f / (float)max(la, 1);
}
// merged H0|H1 incidence fill: i in [0,2E), value = edge id (i mod E)
__global__ __launch_bounds__(256)
void k_fillC2(const int* __restrict__ H, int* __restrict__ cur,
              int* __restrict__ ent, int n2, int E) {
  int i = blockIdx.x * 256 + threadIdx.x;
  if (i >= n2) return;
  int pos = atomicAdd(&cur[H[i]], 1);
  ent[pos] = (i >= E) ? i - E : i;
}
__global__ __launch_bounds__(256)
void k_fillD(const int* __restrict__ dstA, const int* __restrict__ srcA,
             int* __restrict__ cur, int* __restrict__ ent, int n) {
  int e = blockIdx.x * 256 + threadIdx.x;
  if (e >= n) return;
  int pos = atomicAdd(&cur[dstA[e]], 1);
  ent[pos] = srcA[e];
}
__global__ __launch_bounds__(256)
void k_rdeg(const int* __restrict__ ptr, float* __restrict__ r, int n) {
  int i = blockIdx.x * 256 + threadIdx.x;
  if (i < n) r[i] = 1.0f / fmaxf((float)(ptr[i + 1] - ptr[i]), 1.0f);
}

// ---------------- dense MFMA GEMM (split-bf16, truncation split), 64-row tile ----
// C1 = act( rowmul(reluA(A)) @ W1 ) (+beta1*C1); if DUAL: C2 = act( ... @ W2 ).
// In-place C1==A is safe (each block stages its own rows before writing them).
#define MG_SWEEP(WP, ACC)                                                       \
  {                                                                             \
    bf16x8 Bh[2][4], Bl[2][4];                                                  \
    _Pragma("unroll")                                                           \
    for (int np = 0; np < 2; ++np) {                                            \
      int n = (wv * 2 + np) * 16 + nrow;                                        \
      _Pragma("unroll")                                                         \
      for (int kc = 0; kc < 4; ++kc) {                                          \
        int kr0 = kh * 128 + kc * 32 + kg * 8;                                  \
        _Pragma("unroll")                                                       \
        for (int j = 0; j < 8; ++j) {                                           \
          float w = (WP)[(size_t)(kr0 + j) * 128 + n];                          \
          unsigned int hi = __float_as_uint(w) >> 16;                           \
          float lo = w - bf2f(hi);                                              \
          Bh[np][kc][j] = (short)(unsigned short)hi;                            \
          Bl[np][kc][j] = (short)(unsigned short)(__float_as_uint(lo) >> 16);   \
        }                                                                       \
      }                                                                         \
    }                                                                           \
    _Pragma("unroll")                                                           \
    for (int kc = 0; kc < 4; ++kc) {                                            \
      _Pragma("unroll")                                                         \
      for (int m = 0; m < 4; ++m) {                                             \
        int ss = m * 16 + nrow;                                                 \
        int idx = ss * 128 + ((kc * 32 + kg * 8) ^ ((ss & 7) << 3));            \
        bf16x8 ah = *(const bf16x8*)(sAh + idx);                                \
        bf16x8 al = *(const bf16x8*)(sAl + idx);                                \
        _Pragma("unroll")                                                       \
        for (int np = 0; np < 2; ++np) {                                        \
          ACC[m][np] = __builtin_amdgcn_mfma_f32_16x16x32_bf16(ah, Bh[np][kc], ACC[m][np], 0, 0, 0); \
          ACC[m][np] = __builtin_amdgcn_mfma_f32_16x16x32_bf16(al, Bh[np][kc], ACC[m][np], 0, 0, 0); \
          ACC[m][np] = __builtin_amdgcn_mfma_f32_16x16x32_bf16(ah, Bl[np][kc], ACC[m][np], 0, 0, 0); \
        }                                                                       \
      }                                                                         \
    }                                                                           \
  }

template <int DUAL>
__global__ __launch_bounds__(256)
void k_mgemm(int M, const float* __restrict__ A, int K,
             const float* __restrict__ W1, const float* __restrict__ W2,
             const float* __restrict__ dgA, int reluA, int act,
             float* __restrict__ C1, float* __restrict__ C2, int beta1)
{
  __shared__ __align__(16) unsigned char smem[34816];
  unsigned short* sAh = (unsigned short*)smem;            // [64][128] bf16 hi
  unsigned short* sAl = (unsigned short*)(smem + 16384);  // [64][128] bf16 lo
  float* stage = (float*)smem;                            // [64][132] f32 epilogue

  const int t = threadIdx.x, wv = t >> 6;
  const int tr = t >> 4, tc = t & 15;
  const int nrow = (t & 63) & 15, kg = (t & 63) >> 4;
  const int row0 = blockIdx.x * 64;

  f32x4 acc1[4][2], acc2[4][2];
  #pragma unroll
  for (int m = 0; m < 4; ++m)
    #pragma unroll
    for (int np = 0; np < 2; ++np) {
      acc1[m][np] = (f32x4){0.f, 0.f, 0.f, 0.f};
      if (DUAL) acc2[m][np] = (f32x4){0.f, 0.f, 0.f, 0.f};
    }

  const int nkh = K >> 7;
  #pragma unroll 1
  for (int kh = 0; kh < nkh; ++kh) {
    if (kh) __syncthreads();           // sA reads of previous half done
    #pragma unroll
    for (int j = 0; j < 8; ++j) {
      int idx = t + j * 256;           // float4 id, 0..2047
      int r = idx >> 5, c4 = idx & 31;
      int gr = row0 + r; if (gr > M - 1) gr = M - 1;
      float4 va = *(const float4*)(A + (size_t)gr * K + kh * 128 + c4 * 4);
      if (reluA) {
        va.x = fmaxf(va.x, 0.f); va.y = fmaxf(va.y, 0.f);
        va.z = fmaxf(va.z, 0.f); va.w = fmaxf(va.w, 0.f);
      }
      if (dgA) {
        float sc = dgA[gr];
        va.x *= sc; va.y *= sc; va.z *= sc; va.w *= sc;
      }
      float v[4] = {va.x, va.y, va.z, va.w};
      unsigned int h[4], l[4];
      #pragma unroll
      for (int q = 0; q < 4; ++q) {
        h[q] = __float_as_uint(v[q]) >> 16;                  // truncation split
        l[q] = __float_as_uint(v[q] - bf2f(h[q])) >> 16;
      }
      int bidx = r * 128 + ((c4 * 4) ^ ((r & 7) << 3));
      uint2 ph = {h[0] | (h[1] << 16), h[2] | (h[3] << 16)};
      uint2 pl = {l[0] | (l[1] << 16), l[2] | (l[3] << 16)};
      *(uint2*)(sAh + bidx) = ph;
      *(uint2*)(sAl + bidx) = pl;
    }
    __syncthreads();

    MG_SWEEP(W1, acc1);
    if (DUAL) MG_SWEEP(W2, acc2);
  }

  __syncthreads();
  #pragma unroll
  for (int m = 0; m < 4; ++m)
    #pragma unroll
    for (int np = 0; np < 2; ++np)
      #pragma unroll
      for (int r = 0; r < 4; ++r)
        stage[(m * 16 + kg * 4 + r) * 132 + (wv * 2 + np) * 16 + nrow] = acc1[m][np][r];
  __syncthreads();
  #pragma unroll
  for (int i = 0; i < 4; ++i) {
    int s = tr * 4 + i, gr = row0 + s;
    if (gr >= M) continue;
    const float* sp = stage + s * 132 + tc * 8;
    float4 v0 = *(const float4*)sp, v1 = *(const float4*)(sp + 4);
    float o[8] = {v0.x, v0.y, v0.z, v0.w, v1.x, v1.y, v1.z, v1.w};
    #pragma unroll
    for (int j2 = 0; j2 < 8; ++j2) {
      float vv = o[j2];
      if (act == 1)      vv = fmaxf(vv, 0.f);
      else if (act == 2) vv = vv > 0.f ? vv : 0.2f * vv;
      o[j2] = vv;
    }
    float* p = C1 + (size_t)gr * 128 + tc * 8;
    if (beta1) {
      float4 c0 = *(const float4*)p, c1 = *(const float4*)(p + 4);
      o[0] += c0.x; o[1] += c0.y; o[2] += c0.z; o[3] += c0.w;
      o[4] += c1.x; o[5] += c1.y; o[6] += c1.z; o[7] += c1.w;
    }
    *(float4*)p       = *(const float4*)&o[0];
    *(float4*)(p + 4) = *(const float4*)&o[4];
  }
  if (DUAL) {
    __syncthreads();
    #pragma unroll
    for (int m = 0; m < 4; ++m)
      #pragma unroll
      for (int np = 0; np < 2; ++np)
        #pragma unroll
        for (int r = 0; r < 4; ++r)
          stage[(m * 16 + kg * 4 + r) * 132 + (wv * 2 + np) * 16 + nrow] = acc2[m][np][r];
    __syncthreads();
    #pragma unroll
    for (int i = 0; i < 4; ++i) {
      int s = tr * 4 + i, gr = row0 + s;
      if (gr >= M) continue;
      const float* sp = stage + s * 132 + tc * 8;
      float4 v0 = *(const float4*)sp, v1 = *(const float4*)(sp + 4);
      float o[8] = {v0.x, v0.y, v0.z, v0.w, v1.x, v1.y, v1.z, v1.w};
      #pragma unroll
      for (int j2 = 0; j2 < 8; ++j2) {
        float vv = o[j2];
        if (act == 1)      vv = fmaxf(vv, 0.f);
        else if (act == 2) vv = vv > 0.f ? vv : 0.2f * vv;
        o[j2] = vv;
      }
      float* p = C2 + (size_t)gr * 128 + tc * 8;
      *(float4*)p       = *(const float4*)&o[0];
      *(float4*)(p + 4) = *(const float4*)&o[4];
    }
  }
}

// ---------------- fused TSA1 (split-bf16 MFMA): ----------------
// BUF[e] = bf16( et[e]@Ws + mean_{s in A(e)} et[s] @ Wn ), 64 segs/block.
__global__ __launch_bounds__(256)
void k_tsa1(const float* __restrict__ et,
            const int* __restrict__ rp, const int* __restrict__ ent,
            const float* __restrict__ Ws, const float* __restrict__ Wn,
            unsigned short* __restrict__ BUF)
{
  __shared__ __align__(16) unsigned char smem[34816];
  unsigned short* sAh = (unsigned short*)smem;            // [64][128] bf16 hi
  unsigned short* sAl = (unsigned short*)(smem + 16384);  // [64][128] bf16 lo
  int*   sEnt  = (int*)(smem + 32768);                    // 512 ints
  float* stage = (float*)smem;                            // [64][132] f32 (epilogue)

  const int t = threadIdx.x, wv = t >> 6, lane = t & 63;
  const int tr = t >> 4, tc = t & 15;
  const int nrow = lane & 15, kg = lane >> 4;
  const int seg0 = blockIdx.x * 64;
  const int segbase = seg0 + wv * 16;

  int rpv = (lane <= 16) ? rp[segbase + lane] : 0;
  int nxtv = __shfl(rpv, (lane + 1) & 63);
  float invv = 1.f / fmaxf((float)(nxtv - rpv), 1.f);   // valid lanes 0..15

  const int base = rp[seg0];
  const int cnt  = rp[seg0 + 64] - base;
  const int lim  = cnt < 512 ? cnt : 512;
  for (int i = t; i < lim; i += 256) sEnt[i] = ent[base + i];

  // direct half (k = lane): coalesced loads, truncation split, swizzled writes
  {
    float dv[16];
    #pragma unroll
    for (int i = 0; i < 16; ++i)
      dv[i] = et[(size_t)(segbase + i) * 64 + lane];
    #pragma unroll
    for (int i = 0; i < 16; ++i) {
      int ss = wv * 16 + i;
      unsigned int hi = __float_as_uint(dv[i]) >> 16;
      float lo = dv[i] - bf2f(hi);
      int idx = ss * 128 + (lane ^ ((ss & 7) << 3));
      sAh[idx] = (unsigned short)hi;
      sAl[idx] = (unsigned short)(__float_as_uint(lo) >> 16);
    }
  }

  // B fragments from global (L2-resident), truncation split
  bf16x8 Bh[2][4], Bl[2][4];
  #pragma unroll
  for (int np = 0; np < 2; ++np) {
    int n = (wv * 2 + np) * 16 + nrow;
    #pragma unroll
    for (int kc = 0; kc < 4; ++kc) {
      const float* Wp = (kc < 2) ? Ws : Wn;
      int kr0 = (kc & 1) * 32 + kg * 8;
      #pragma unroll
      for (int j = 0; j < 8; ++j) {
        float w = Wp[(size_t)(kr0 + j) * 128 + n];
        unsigned int hi = __float_as_uint(w) >> 16;
        float lo = w - bf2f(hi);
        Bh[np][kc][j] = (short)(unsigned short)hi;
        Bl[np][kc][j] = (short)(unsigned short)(__float_as_uint(lo) >> 16);
      }
    }
  }
  __syncthreads();   // sEnt ready

  // gathered half (k = 64+lane): flatten over entries, 8 row-loads in flight
  {
    int q0 = __shfl(rpv, 0);
    int q1 = __shfl(rpv, 16);
    int c = 0;
    int b_next = __shfl(rpv, 1);
    float idg = __shfl(invv, 0);
    float a = 0.f;
    #pragma unroll 1
    for (int j = q0; j < q1; j += 8) {
      float x[8];
      #pragma unroll
      for (int u = 0; u < 8; ++u) {
        int jj = j + u; jj = jj < q1 ? jj : q1 - 1;
        int ix = jj - base;
        int s = (ix < 512) ? sEnt[ix] : ent[jj];
        x[u] = et[(size_t)s * 64 + lane];
      }
      #pragma unroll
      for (int u = 0; u < 8; ++u) {
        int jj = j + u;
        if (jj >= q1) break;
        while (jj >= b_next) {        // column c complete -> flush
          float v = a * idg;
          int ss = wv * 16 + c;
          unsigned int hi = __float_as_uint(v) >> 16;
          float lo = v - bf2f(hi);
          int idx = ss * 128 + ((64 + lane) ^ ((ss & 7) << 3));
          sAh[idx] = (unsigned short)hi;
          sAl[idx] = (unsigned short)(__float_as_uint(lo) >> 16);
          a = 0.f;
          ++c;
          b_next = __shfl(rpv, c + 1);
          idg = __shfl(invv, c);
        }
        a += x[u];
      }
    }
    #pragma unroll 1
    for (;;) {                        // flush current + trailing columns
      float v = a * idg;
      int ss = wv * 16 + c;
      unsigned int hi = __float_as_uint(v) >> 16;
      float lo = v - bf2f(hi);
      int idx = ss * 128 + ((64 + lane) ^ ((ss & 7) << 3));
      sAh[idx] = (unsigned short)hi;
      sAl[idx] = (unsigned short)(__float_as_uint(lo) >> 16);
      a = 0.f;
      if (++c >= 16) break;
      idg = __shfl(invv, c);
    }
  }
  __syncthreads();

  f32x4 acc[4][2];
  #pragma unroll
  for (int m = 0; m < 4; ++m)
    #pragma unroll
    for (int np = 0; np < 2; ++np)
      acc[m][np] = (f32x4){0.f, 0.f, 0.f, 0.f};

  #pragma unroll
  for (int kc = 0; kc < 4; ++kc) {
    #pragma unroll
    for (int m = 0; m < 4; ++m) {
      int ss = m * 16 + nrow;
      int kbase = kc * 32 + kg * 8;
      int idx = ss * 128 + (kbase ^ ((ss & 7) << 3));
      bf16x8 ah = *(const bf16x8*)(sAh + idx);
      bf16x8 al = *(const bf16x8*)(sAl + idx);
      #pragma unroll
      for (int np = 0; np < 2; ++np) {
        acc[m][np] = __builtin_amdgcn_mfma_f32_16x16x32_bf16(ah, Bh[np][kc], acc[m][np], 0, 0, 0);
        acc[m][np] = __builtin_amdgcn_mfma_f32_16x16x32_bf16(al, Bh[np][kc], acc[m][np], 0, 0, 0);
        acc[m][np] = __builtin_amdgcn_mfma_f32_16x16x32_bf16(ah, Bl[np][kc], acc[m][np], 0, 0, 0);
      }
    }
  }

  __syncthreads();
  #pragma unroll
  for (int m = 0; m < 4; ++m)
    #pragma unroll
    for (int np = 0; np < 2; ++np)
      #pragma unroll
      for (int r = 0; r < 4; ++r)
        stage[(m * 16 + kg * 4 + r) * 132 + (wv * 2 + np) * 16 + nrow] = acc[m][np][r];
  __syncthreads();
  #pragma unroll
  for (int i = 0; i < 4; ++i) {
    int s = tr * 4 + i;
    const float* sp = stage + s * 132 + tc * 8;
    float4 v0 = *(const float4*)sp;
    float4 v1 = *(const float4*)(sp + 4);
    unsigned int pk[4];
    pk[0] = f2bf(v0.x) | (f2bf(v0.y) << 16);
    pk[1] = f2bf(v0.z) | (f2bf(v0.w) << 16);
    pk[2] = f2bf(v1.x) | (f2bf(v1.y) << 16);
    pk[3] = f2bf(v1.z) | (f2bf(v1.w) << 16);
    uint4 st = {pk[0], pk[1], pk[2], pk[3]};
    *(uint4*)(BUF + (size_t)(seg0 + s) * 128 + tc * 8) = st;
  }
}

// ---------------- balanced chunked pooling (bf16 rows, relu, opt weights) ----
// One wave per 256-entry chunk; binary-search rp for the start segment; flush
// chunk-owned segments with direct RMW, boundary segments with atomicAdd.
// O must be zero-initialized. O[seg] += sum_{j in seg} w_j * relu(SRC[ent[j]]).
__global__ __launch_bounds__(256)
void k_poolb(const int* __restrict__ rp, const int* __restrict__ ent,
             const float* __restrict__ entw,
             const unsigned short* __restrict__ SRC,
             float* __restrict__ O, int nseg, int total)
{
  const int wv = threadIdx.x >> 6, lane = threadIdx.x & 63;
  const int chunk = blockIdx.x * 4 + wv;
  const int c0 = chunk * 256;
  if (c0 >= total) return;
  int c1 = c0 + 256; if (c1 > total) c1 = total;

  int lo = 0, hi = nseg;                 // rp[lo] <= c0 < rp[hi]
  while (lo + 1 < hi) {
    int mid = (lo + hi) >> 1;
    if (rp[mid] <= c0) lo = mid; else hi = mid;
  }
  int seg = lo;
  int sstart = rp[seg];
  int send = rp[seg + 1];
  float a0 = 0.f, a1 = 0.f;

  #pragma unroll 1
  for (int j = c0; j < c1; j += 8) {
    int ids[8]; float w[8];
    #pragma unroll
    for (int u = 0; u < 8; ++u) {
      int jj = j + u; jj = jj < c1 ? jj : c1 - 1;
      ids[u] = ent[jj];
      w[u] = entw ? entw[jj] : 1.f;
    }
    unsigned int uv[8];
    #pragma unroll
    for (int u = 0; u < 8; ++u)
      uv[u] = *(const unsigned int*)(SRC + (size_t)ids[u] * 128 + 2 * lane);
    #pragma unroll
    for (int u = 0; u < 8; ++u) {
      int jj = j + u;
      if (jj >= c1) break;
      while (jj >= send) {               // segment complete -> flush
        float* p = O + (size_t)seg * 128;
        if (sstart >= c0 && send <= c1) {
          p[2 * lane]     += a0;
          p[2 * lane + 1] += a1;
        } else {
          atomicAdd(p + 2 * lane, a0);
          atomicAdd(p + 2 * lane + 1, a1);
        }
        a0 = a1 = 0.f;
        ++seg; sstart = send; send = rp[seg + 1];
      }
      a0 = fmaf(w[u], fmaxf(bf2f(uv[u] & 0xffffu), 0.f), a0);
      a1 = fmaf(w[u], fmaxf(bf2f(uv[u] >> 16),     0.f), a1);
    }
  }
  {                                       // final flush (possibly partial seg)
    float* p = O + (size_t)seg * 128;
    if (sstart >= c0 && send <= c1) {
      p[2 * lane]     += a0;
      p[2 * lane + 1] += a1;
    } else {
      atomicAdd(p + 2 * lane, a0);
      atomicAdd(p + 2 * lane + 1, a1);
    }
  }
}

// ---------------- balanced chunked segment-mean (f32 rows): O[seg] += mean ----
__global__ __launch_bounds__(256)
void k_poolf(const int* __restrict__ rp, const int* __restrict__ ent,
             const float* __restrict__ SRC, float* __restrict__ O,
             int nseg, int total)
{
  const int wv = threadIdx.x >> 6, lane = threadIdx.x & 63;
  const int chunk = blockIdx.x * 4 + wv;
  const int c0 = chunk * 256;
  if (c0 >= total) return;
  int c1 = c0 + 256; if (c1 > total) c1 = total;

  int lo = 0, hi = nseg;
  while (lo + 1 < hi) {
    int mid = (lo + hi) >> 1;
    if (rp[mid] <= c0) lo = mid; else hi = mid;
  }
  int seg = lo;
  int sstart = rp[seg];
  int send = rp[seg + 1];
  float a0 = 0.f, a1 = 0.f;

  #pragma unroll 1
  for (int j = c0; j < c1; j += 8) {
    int ids[8];
    #pragma unroll
    for (int u = 0; u < 8; ++u) {
      int jj = j + u; jj = jj < c1 ? jj : c1 - 1;
      ids[u] = ent[jj];
    }
    float2 v[8];
    #pragma unroll
    for (int u = 0; u < 8; ++u)
      v[u] = ((const float2*)(SRC + (size_t)ids[u] * 128))[lane];
    #pragma unroll
    for (int u = 0; u < 8; ++u) {
      int jj = j + u;
      if (jj >= c1) break;
      while (jj >= send) {               // segment complete -> flush mean
        float sc = 1.f / fmaxf((float)(send - sstart), 1.f);
        float* p = O + (size_t)seg * 128;
        if (sstart >= c0 && send <= c1) {
          p[2 * lane]     += a0 * sc;
          p[2 * lane + 1] += a1 * sc;
        } else {
          atomicAdd(p + 2 * lane, a0 * sc);
          atomicAdd(p + 2 * lane + 1, a1 * sc);
        }
        a0 = a1 = 0.f;
        ++seg; sstart = send; send = rp[seg + 1];
      }
      a0 += v[u].x; a1 += v[u].y;
    }
  }
  {
    float sc = 1.f / fmaxf((float)(send - sstart), 1.f);
    float* p = O + (size_t)seg * 128;
    if (sstart >= c0 && send <= c1) {
      p[2 * lane]     += a0 * sc;
      p[2 * lane + 1] += a1 * sc;
    } else {
      atomicAdd(p + 2 * lane, a0 * sc);
      atomicAdd(p + 2 * lane + 1, a1 * sc);
    }
  }
}

// ---------------- fused attention: online softmax + PV, one wave per node ----------------
__global__ __launch_bounds__(256)
void k_attn(const int* __restrict__ rp, const int* __restrict__ ent,
            const float* __restrict__ q, const float* __restrict__ kb,
            const float* __restrict__ vb, float* __restrict__ o, int nseg)
{
  int wv = threadIdx.x >> 6, lane = threadIdx.x & 63;
  int seg = blockIdx.x * 4 + wv;
  if (seg >= nseg) return;
  int p0 = rp[seg], p1 = rp[seg + 1];
  if (p0 >= p1) return;
  float2 q2 = ((const float2*)(q + (size_t)seg * 128))[lane];
  float m = -1e30f, l = 0.f, o0 = 0.f, o1 = 0.f;
  #pragma unroll 1
  for (int j = p0; j < p1; j += 4) {
    int s[4];
    #pragma unroll
    for (int i = 0; i < 4; ++i) {
      int jj = j + i; jj = jj < p1 ? jj : p1 - 1;
      s[i] = ent[jj];
    }
    float2 k2[4], v2[4];
    #pragma unroll
    for (int i = 0; i < 4; ++i)
      k2[i] = ((const float2*)(kb + (size_t)s[i] * 128))[lane];
    #pragma unroll
    for (int i = 0; i < 4; ++i)
      v2[i] = ((const float2*)(vb + (size_t)s[i] * 128))[lane];
    float d[4];
    #pragma unroll
    for (int i = 0; i < 4; ++i) d[i] = fmaf(q2.x, k2[i].x, q2.y * k2[i].y);
    #pragma unroll
    for (int off = 1; off < 64; off <<= 1) {
      #pragma unroll
      for (int i = 0; i < 4; ++i) d[i] += __shfl_xor(d[i], off);
    }
    float sc[4];
    #pragma unroll
    for (int i = 0; i < 4; ++i) {
      float v = d[i] * 0.088388347648318447f;      // 1/sqrt(128)
      v = v > 0.f ? v : 0.2f * v;                  // leaky 0.2
      sc[i] = (j + i < p1) ? v : -1e30f;
    }
    float mb = fmaxf(fmaxf(sc[0], sc[1]), fmaxf(sc[2], sc[3]));
    float mn = fmaxf(m, mb);
    float scale = expf(m - mn);
    float e[4];
    #pragma unroll
    for (int i = 0; i < 4; ++i)
      e[i] = (j + i < p1) ? expf(sc[i] - mn) : 0.f;
    l  = l  * scale + ((e[0] + e[1]) + (e[2] + e[3]));
    o0 = o0 * scale + ((e[0] * v2[0].x + e[1] * v2[1].x) + (e[2] * v2[2].x + e[3] * v2[3].x));
    o1 = o1 * scale + ((e[0] * v2[0].y + e[1] * v2[1].y) + (e[2] * v2[2].y + e[3] * v2[3].y));
    m = mn;
  }
  float inv = 1.f / fmaxf(l, 1e-9f);
  float2* orow = (float2*)(o + (size_t)seg * 128);
  float2 cur = orow[lane];
  cur.x += o0 * inv; cur.y += o1 * inv;
  orow[lane] = cur;
}

// ---------------- classifier + log_softmax ----------------
__global__ __launch_bounds__(256)
void k_out(const float* __restrict__ attn, const float* __restrict__ Wout,
           float* __restrict__ out, int n) {
  __shared__ float sW[128 * 64];
  for (int i = threadIdx.x; i < 128 * 64; i += 256) sW[i] = Wout[i];
  __syncthreads();
  int wave = threadIdx.x >> 6, lane = threadIdx.x & 63;
  int row = blockIdx.x * 4 + wave;
  if (row >= n) return;
  const float* a = attn + (size_t)row * 128;
  float z = 0.f;
  #pragma unroll 8
  for (int k = 0; k < 128; ++k) z = fmaf(a[k], sW[k * 64 + lane], z);
  float mx = z;
  #pragma unroll
  for (int off = 32; off; off >>= 1) mx = fmaxf(mx, __shfl_xor(mx, off));
  float ee = expf(z - mx);
  float ss = ee;
  #pragma unroll
  for (int off = 32; off; off >>= 1) ss += __shfl_xor(ss, off);
  out[(size_t)row * 64 + lane] = z - mx - logf(ss);
}

extern "C" void kernel_launch(void* const* d_in, const int* in_sizes, int n_in,
                              void* d_out, int out_size, void* d_ws, size_t ws_size,
                              hipStream_t stream) {
  (void)in_sizes; (void)n_in; (void)out_size;
  const float* x        = (const float*)d_in[0];
  const float* et       = (const float*)d_in[1];
  const int*   H0       = (const int*)d_in[2];   // H0,H1 contiguous
  const int*   src      = (const int*)d_in[3];
  const int*   dst      = src + Ee;
  const int*   src_lg   = (const int*)d_in[4];
  const int*   dst_lg   = src_lg + LGEe;
  const float* W_tsa1_s = (const float*)d_in[5];
  const float* W_tsa1_n = (const float*)d_in[6];
  const float* W_tsa2_s = (const float*)d_in[7];
  const float* W_tsa2_n = (const float*)d_in[8];
  const float* W_etn    = (const float*)d_in[9];
  const float* W_eg_lin = (const float*)d_in[10];
  const float* W_ea_s   = (const float*)d_in[11];
  const float* W_ea_n   = (const float*)d_in[12];
  const float* W_an1_s  = (const float*)d_in[13];
  const float* W_an1_n  = (const float*)d_in[14];
  const float* W_an2_s  = (const float*)d_in[15];
  const float* W_an2_n  = (const float*)d_in[16];
  const float* Wq       = (const float*)d_in[17];
  const float* Wk       = (const float*)d_in[18];
  const float* Wv       = (const float*)d_in[19];
  const float* W_out    = (const float*)d_in[20];
  float* out = (float*)d_out;

  // ---- workspace carve ----
  char* wp = (char*)d_ws;
  size_t avail = ws_size;
  auto alloc = [&](size_t bytes) -> void* {
    void* r = (void*)wp;
    size_t pad = (bytes + 255) & ~(size_t)255;
    wp += pad; avail = (avail >= pad) ? avail - pad : 0;
    return r;
  };
  const size_t NH = (size_t)Nn * 128;
  unsigned short* BUF = (unsigned short*)alloc((size_t)Ee * 128 * 2); // 204.8MB bf16 h1
  float* aggN  = (float*)alloc(NH * 4);
  float* aggS  = (float*)alloc(NH * 4);
  int* ptrA  = (int*)alloc(((size_t)Ee + 1) * 4);
  int* cntA  = (int*)alloc((size_t)Ee * 4);
  int* entA  = (int*)alloc((size_t)LGEe * 4);
  int* ptrB  = (int*)alloc(((size_t)Nn + 1) * 4);
  int* cntB  = (int*)alloc((size_t)Nn * 4);
  int* entBs = (int*)alloc((size_t)2 * LGEe * 4);
  float* entBw = (float*)alloc((size_t)2 * LGEe * 4);
  int* ptrC  = (int*)alloc(((size_t)Nn + 1) * 4);
  int* cntC  = (int*)alloc((size_t)Nn * 4);
  int* entC  = (int*)alloc((size_t)2 * Ee * 4);
  int* ptrD  = (int*)alloc(((size_t)Nn + 1) * 4);
  int* cntD  = (int*)alloc((size_t)Nn * 4);
  int* entD  = (int*)alloc((size_t)Ee * 4);
  float* rdegN = (float*)alloc((size_t)Nn * 4);
  int* bsum  = (int*)alloc(2048 * 4);
  if (avail == 0 && wp > (char*)d_ws + ws_size) return;  // ws too small: clean fail

  // node-phase f32 arrays overlay BUF (dead after pools): 8 x 25.6MB
  float* er  = (float*)BUF + 0 * NH;
  float* ae  = (float*)BUF + 1 * NH;
  float* hn  = (float*)BUF + 2 * NH;
  float* hn2 = (float*)BUF + 3 * NH;
  float* qb  = (float*)BUF + 4 * NH;
  float* kb  = (float*)BUF + 5 * NH;
  float* vb  = (float*)BUF + 6 * NH;
  float* tmp = (float*)BUF + 7 * NH;

  auto cdiv = [](long a, long b) { return (int)((a + b - 1) / b); };
  auto scan = [&](int* cnt, int* ptr, int n, int total) {
    int nb = cdiv(n, 1024);
    k_scan1<<<nb, 256, 0, stream>>>(cnt, ptr, bsum, n);
    k_scan2<<<1, 1024, 0, stream>>>(bsum, nb);
    k_scan3<<<cdiv(n, 256), 256, 0, stream>>>(ptr, bsum, n, total, cnt); // cnt becomes cur
  };

  const int gLG = cdiv(LGEe, 256), gEe = cdiv(Ee, 256);
  const int g2E = cdiv(2 * Ee, 256), g2LG = cdiv(2 * LGEe, 256);

  // ---- CSR A: line-graph by dst_lg (E segments) ----
  hipMemsetAsync(cntA, 0, (size_t)Ee * 4, stream);
  k_count_direct<<<gLG, 256, 0, stream>>>(dst_lg, cntA, LGEe);
  scan(cntA, ptrA, Ee, LGEe);
  k_fillA<<<gLG, 256, 0, stream>>>(dst_lg, src_lg, cntA, entA, LGEe);

  // ---- CSR B: composed H[b][dst_lg[m]] (N segments, 2*LGE), merged passes ----
  hipMemsetAsync(cntB, 0, (size_t)Nn * 4, stream);
  k_count_comp2<<<g2LG, 256, 0, stream>>>(H0, dst_lg, cntB, 2 * LGEe, LGEe, Ee);
  scan(cntB, ptrB, Nn, 2 * LGEe);
  k_fillB2<<<g2LG, 256, 0, stream>>>(H0, dst_lg, src_lg, ptrA, cntB, entBs, entBw,
                                     2 * LGEe, LGEe, Ee);

  // ---- CSR C: H incidence (N segments, 2E entries), merged H0|H1 passes ----
  hipMemsetAsync(cntC, 0, (size_t)Nn * 4, stream);
  k_count_direct<<<g2E, 256, 0, stream>>>(H0, cntC, 2 * Ee);
  scan(cntC, ptrC, Nn, 2 * Ee);
  k_fillC2<<<g2E, 256, 0, stream>>>(H0, cntC, entC, 2 * Ee, Ee);

  // ---- CSR D: raw graph by dst (N segments, E entries, value = src) ----
  hipMemsetAsync(cntD, 0, (size_t)Nn * 4, stream);
  k_count_direct<<<gEe, 256, 0, stream>>>(dst, cntD, Ee);
  scan(cntD, ptrD, Nn, Ee);
  k_fillD<<<gEe, 256, 0, stream>>>(dst, src, cntD, entD, Ee);
  k_rdeg<<<cdiv(Nn, 256), 256, 0, stream>>>(ptrC, rdegN, Nn);

  const int gM64  = cdiv(Nn, 64);                       // 782
  const int gW    = cdiv(Nn, 4);                        // 12500
  const int gP2   = cdiv(cdiv(2 * LGEe, 256), 4);       // 3125
  const int gP1   = cdiv(cdiv(2 * Ee, 256), 4);         // 1563
  const int gPf   = cdiv(cdiv(Ee, 256), 4);             // 782

  // ---- TSA layer 1, fused self+nbr -> BUF (bf16, pre-relu), split-bf16 MFMA ----
  k_tsa1<<<Ee / 64, 256, 0, stream>>>(et, ptrA, entA, W_tsa1_s, W_tsa1_n, BUF);

  // ---- TSA layer 2 + EdgeToNode via balanced flat pooling + MFMA GEMMs ----
  hipMemsetAsync(aggN, 0, NH * 4, stream);
  hipMemsetAsync(aggS, 0, NH * 4, stream);
  k_poolb<<<gP2, 256, 0, stream>>>(ptrB, entBs, entBw, BUF, aggN, Nn, 2 * LGEe);
  k_poolb<<<gP1, 256, 0, stream>>>(ptrC, entC, nullptr, BUF, aggS, Nn, 2 * Ee);
  k_mgemm<0><<<gM64, 256, 0, stream>>>(Nn, aggN, 128, W_tsa2_n, nullptr, nullptr, 0, 0, aggN, nullptr, 0); // in-place
  k_mgemm<0><<<gM64, 256, 0, stream>>>(Nn, aggS, 128, W_tsa2_s, nullptr, nullptr, 0, 0, aggN, nullptr, 1);
  k_mgemm<0><<<gM64, 256, 0, stream>>>(Nn, aggN, 128, W_etn, nullptr, rdegN, 0, 2, tmp, nullptr, 0);
  k_mgemm<0><<<gM64, 256, 0, stream>>>(Nn, tmp, 128, W_eg_lin, nullptr, nullptr, 0, 0, er, nullptr, 0);

  // ---- edge_aggr SAGE (dual: ae = er@Ws, tmp = er@Wn) ----
  k_mgemm<1><<<gM64, 256, 0, stream>>>(Nn, er, 128, W_ea_s, W_ea_n, nullptr, 0, 0, ae, tmp, 0);
  k_poolf<<<gPf, 256, 0, stream>>>(ptrD, entD, tmp, ae, Nn, Ee);

  // ---- attr_node_model (dual pairs; hn kept pre-relu, relu applied on read) ----
  k_mgemm<1><<<gM64, 256, 0, stream>>>(Nn, x, 256, W_an1_s, W_an1_n, nullptr, 0, 0, hn, tmp, 0);
  k_poolf<<<gPf, 256, 0, stream>>>(ptrD, entD, tmp, hn, Nn, Ee);
  k_mgemm<1><<<gM64, 256, 0, stream>>>(Nn, hn, 128, W_an2_s, W_an2_n, nullptr, 1, 0, hn2, tmp, 0);
  k_poolf<<<gPf, 256, 0, stream>>>(ptrD, entD, tmp, hn2, Nn, Ee);

  // ---- MixAttention (fused online softmax; out accumulated into hn2) ----
  k_mgemm<0><<<gM64, 256, 0, stream>>>(Nn, hn2, 128, Wq, nullptr, nullptr, 0, 0, qb, nullptr, 0);
  k_mgemm<1><<<gM64, 256, 0, stream>>>(Nn, ae, 128, Wk, Wv, nullptr, 0, 0, kb, vb, 0);
  k_attn<<<gW, 256, 0, stream>>>(ptrD, entD, qb, kb, vb, hn2, Nn);

  // ---- classifier + log_softmax ----
  k_out<<<gW, 256, 0, stream>>>(hn2, W_out, out, Nn);
}